// Round 3
// baseline (411.609 us; speedup 1.0000x reference)
//
#include <hip/hip_runtime.h>
#include <hip/hip_bf16.h>

#define F_DIM 256
#define N_DIM 128
#define B_DIM 4096

typedef float f32x4v __attribute__((ext_vector_type(4)));
typedef short s16x8 __attribute__((ext_vector_type(8)));
typedef unsigned int u32x2v __attribute__((ext_vector_type(2)));
typedef unsigned int u32x4v __attribute__((ext_vector_type(4)));

__device__ __forceinline__ unsigned short f2bf(float f) {
  union { float f; unsigned u; } v; v.f = f;
  unsigned r = v.u + 0x7fffu + ((v.u >> 16) & 1u);   // RNE
  return (unsigned short)(r >> 16);
}

__device__ __forceinline__ unsigned pk2(float a, float b) {
  union { __hip_bfloat16 h[2]; unsigned u; } v;
  v.h[0] = __float2bfloat16(a);
  v.h[1] = __float2bfloat16(b);
  return v.u;
}

__device__ __forceinline__ void gload16(const void* g, void* l) {
  __builtin_amdgcn_global_load_lds(
      (const __attribute__((address_space(1))) unsigned int*)g,
      (__attribute__((address_space(3))) unsigned int*)l, 16, 0, 0);
}

// ---------------------------------------------------------------------------
// prep_w: w2,w3 (F,128,128) fp32 [i][o] -> per-feature bf16 W^T [o][i],
// row stride 256B, PRE-SWIZZLED so linear global_load_lds lands XOR-swizzled.
// ---------------------------------------------------------------------------
__global__ void prep_w(const float* __restrict__ w2, const float* __restrict__ w3,
                       unsigned int* __restrict__ wTs) {
  __shared__ float tile[128 * 130];
  int m = blockIdx.x;
  const float* src = (m < 256) ? (w2 + (size_t)m * 16384)
                               : (w3 + (size_t)(m - 256) * 16384);
  int t = threadIdx.x;  // 256
  for (int k = 0; k < 64; ++k) {
    int idx = k * 256 + t;
    int i = idx >> 7, o = idx & 127;
    tile[o * 130 + i] = src[idx];
  }
  __syncthreads();
  unsigned int* dst = wTs + (size_t)m * 8192;
  for (int k = 0; k < 32; ++k) {
    int idx = k * 256 + t;
    int o = idx >> 6, i2 = idx & 63;
    unsigned pk = (unsigned)f2bf(tile[o * 130 + 2 * i2]) |
                  ((unsigned)f2bf(tile[o * 130 + 2 * i2 + 1]) << 16);
    dst[(o * 64 + i2) ^ ((o & 7) << 2)] = pk;
  }
}

// ---------------------------------------------------------------------------
// prep_x: x (B,F) -> xT (F,B) fp32
// ---------------------------------------------------------------------------
__global__ void prep_x(const float* __restrict__ x, float* __restrict__ xT) {
  __shared__ float tile[64][65];
  int btile = blockIdx.x & 63;
  int ftile = blockIdx.x >> 6;
  int t = threadIdx.x;  // 256
  for (int k = 0; k < 16; ++k) {
    int idx = k * 256 + t;
    int r = idx >> 6, c = idx & 63;
    tile[r][c] = x[(size_t)(btile * 64 + r) * F_DIM + ftile * 64 + c];
  }
  __syncthreads();
  for (int k = 0; k < 16; ++k) {
    int idx = k * 256 + t;
    int fr = idx >> 6, br = idx & 63;
    xT[(size_t)(ftile * 64 + fr) * B_DIM + btile * 64 + br] = tile[br][fr];
  }
}

// ---------------------------------------------------------------------------
// mlp_persist: one block per feature f (256 blocks, 512 thr = 8 waves).
// W2,W3 staged to LDS once; then 16 batch tiles of 256 rows, 32 rows/wave,
// NO __syncthreads in the loop (wave-private H slabs).
// Layer1 fused into layer2 B-fragments (registers). Biases folded via MFMA
// C-operand. Layer4 fp32 in registers + 2 shuffles.
// ---------------------------------------------------------------------------
__global__ __launch_bounds__(512, 2) void mlp_persist(
    const float* __restrict__ xT, const float* __restrict__ w1,
    const float* __restrict__ b1, const float* __restrict__ b2,
    const float* __restrict__ b3, const float* __restrict__ w4,
    const float* __restrict__ b4, const unsigned int* __restrict__ wTs,
    float* __restrict__ xp) {
  __shared__ __align__(16) char Wb[2][128 * 256];   // 64 KiB: W2^T, W3^T swizzled
  __shared__ __align__(16) char Hb[8][32 * 256];    // 64 KiB: per-wave H2 slabs
  __shared__ __align__(16) float cst[384];          // b2 | b3 | w4

  const int f = blockIdx.x;
  const int t = threadIdx.x;
  const int lane = t & 63, wid = t >> 6;
  const int r16 = lane & 15, g = lane >> 4;
  const int swz = (r16 & 7) << 4;

  // ---- stage W2[f], W3[f] (pre-swizzled bf16) -> LDS, linear gload ----
  {
    const char* s2 = (const char*)(wTs + (size_t)f * 8192);
    const char* s3 = (const char*)(wTs + (size_t)(256 + f) * 8192);
#pragma unroll
    for (int c = 0; c < 4; ++c) {
      int off = (wid * 4 + c) * 1024;
      gload16(s2 + off + lane * 16, &Wb[0][off]);
    }
#pragma unroll
    for (int c = 0; c < 4; ++c) {
      int off = (wid * 4 + c) * 1024;
      gload16(s3 + off + lane * 16, &Wb[1][off]);
    }
    if (t < 96) {
      int which = t >> 5, idx = t & 31;
      const float* src = (which == 0) ? b2 : (which == 1) ? b3 : w4;
      *(f32x4v*)&cst[t * 4] = *(const f32x4v*)&src[f * N_DIM + idx * 4];
    }
  }

  // ---- per-lane w1/b1 constants: i-octet = kk*32 + g*8 (64 VGPRs) ----
  f32x4v w1a[4], w1b[4], b1a[4], b1b[4];
#pragma unroll
  for (int kk = 0; kk < 4; ++kk) {
    const float* wp = w1 + f * N_DIM + kk * 32 + g * 8;
    const float* bp = b1 + f * N_DIM + kk * 32 + g * 8;
    w1a[kk] = *(const f32x4v*)wp;  w1b[kk] = *(const f32x4v*)(wp + 4);
    b1a[kk] = *(const f32x4v*)bp;  b1b[kk] = *(const f32x4v*)(bp + 4);
  }
  const float b4f = b4[f];

  __syncthreads();   // the ONLY block-wide barrier (drains gload_lds + cst)

  char* Hw = Hb[wid];
  const float* xcol = xT + (size_t)f * B_DIM;
  float* xprow = xp + (size_t)f * B_DIM;

  for (int tile = 0; tile < 16; ++tile) {
    const int R = tile * 256 + wid * 32;

    // ---- layer1 fused: build L2 B-fragments in registers ----
    s16x8 pf[2][4];
#pragma unroll
    for (int nt = 0; nt < 2; ++nt) {
      float xv = xcol[R + nt * 16 + r16];
#pragma unroll
      for (int kk = 0; kk < 4; ++kk) {
        u32x4v pk;
        pk[0] = pk2(fmaxf(fmaf(xv, w1a[kk][0], b1a[kk][0]), 0.f),
                    fmaxf(fmaf(xv, w1a[kk][1], b1a[kk][1]), 0.f));
        pk[1] = pk2(fmaxf(fmaf(xv, w1a[kk][2], b1a[kk][2]), 0.f),
                    fmaxf(fmaf(xv, w1a[kk][3], b1a[kk][3]), 0.f));
        pk[2] = pk2(fmaxf(fmaf(xv, w1b[kk][0], b1b[kk][0]), 0.f),
                    fmaxf(fmaf(xv, w1b[kk][1], b1b[kk][1]), 0.f));
        pk[3] = pk2(fmaxf(fmaf(xv, w1b[kk][2], b1b[kk][2]), 0.f),
                    fmaxf(fmaf(xv, w1b[kk][3], b1b[kk][3]), 0.f));
        pf[nt][kk] = __builtin_bit_cast(s16x8, pk);
      }
    }

    // ---- layer 2: acc[mt][nt] = W2^T @ H1^T (+b2 via C-operand) ----
    f32x4v acc[8][2];
    __builtin_amdgcn_s_setprio(1);
#pragma unroll
    for (int mt = 0; mt < 8; ++mt) {
      f32x4v c0 = *(const f32x4v*)&cst[mt * 16 + g * 4];          // b2 frag
      const int rowb = (mt * 16 + r16) * 256 + ((g * 16) ^ swz);
#pragma unroll
      for (int kk = 0; kk < 4; ++kk) {
        s16x8 af = *(const s16x8*)(&Wb[0][0] + (rowb ^ (kk << 6)));
        acc[mt][0] = __builtin_amdgcn_mfma_f32_16x16x32_bf16(
            af, pf[0][kk], kk == 0 ? c0 : acc[mt][0], 0, 0, 0);
        acc[mt][1] = __builtin_amdgcn_mfma_f32_16x16x32_bf16(
            af, pf[1][kk], kk == 0 ? c0 : acc[mt][1], 0, 0, 0);
      }
    }
    __builtin_amdgcn_s_setprio(0);

    // ---- epilogue: H2 -> wave-private slab (relu + pack, swizzled) ----
#pragma unroll
    for (int mt = 0; mt < 8; ++mt)
#pragma unroll
      for (int nt = 0; nt < 2; ++nt) {
        f32x4v v = acc[mt][nt];
        int n = nt * 16 + r16;
        u32x2v d;
        d[0] = pk2(fmaxf(v[0], 0.f), fmaxf(v[1], 0.f));
        d[1] = pk2(fmaxf(v[2], 0.f), fmaxf(v[3], 0.f));
        *(u32x2v*)(Hw + n * 256 + ((mt * 32 + g * 8) ^ ((n & 7) << 4))) = d;
      }

    // ---- layer 3 B-fragments from own slab (same-wave order, no barrier) --
    s16x8 hf[2][4];
#pragma unroll
    for (int nt = 0; nt < 2; ++nt)
#pragma unroll
      for (int kk = 0; kk < 4; ++kk)
        hf[nt][kk] = *(const s16x8*)(Hw + (nt * 16 + r16) * 256 +
                                     (((g * 16) ^ swz) ^ (kk << 6)));

    // ---- layer 3: acc = W3^T @ H2^T (+b3 via C-operand) ----
    __builtin_amdgcn_s_setprio(1);
#pragma unroll
    for (int mt = 0; mt < 8; ++mt) {
      f32x4v c0 = *(const f32x4v*)&cst[128 + mt * 16 + g * 4];    // b3 frag
      const int rowb = (mt * 16 + r16) * 256 + ((g * 16) ^ swz);
#pragma unroll
      for (int kk = 0; kk < 4; ++kk) {
        s16x8 af = *(const s16x8*)(&Wb[1][0] + (rowb ^ (kk << 6)));
        acc[mt][0] = __builtin_amdgcn_mfma_f32_16x16x32_bf16(
            af, hf[0][kk], kk == 0 ? c0 : acc[mt][0], 0, 0, 0);
        acc[mt][1] = __builtin_amdgcn_mfma_f32_16x16x32_bf16(
            af, hf[1][kk], kk == 0 ? c0 : acc[mt][1], 0, 0, 0);
      }
    }
    __builtin_amdgcn_s_setprio(0);

    // ---- layer 4 (fp32): y[n] = sum_o relu(acc)*w4[o], 2 shuffles ----
    float p0 = 0.f, p1 = 0.f;
#pragma unroll
    for (int mt = 0; mt < 8; ++mt) {
      f32x4v w4v = *(const f32x4v*)&cst[256 + mt * 16 + g * 4];
#pragma unroll
      for (int i = 0; i < 4; ++i) {
        p0 = fmaf(fmaxf(acc[mt][0][i], 0.f), w4v[i], p0);
        p1 = fmaf(fmaxf(acc[mt][1][i], 0.f), w4v[i], p1);
      }
    }
    p0 += __shfl_xor(p0, 16, 64);  p0 += __shfl_xor(p0, 32, 64);
    p1 += __shfl_xor(p1, 16, 64);  p1 += __shfl_xor(p1, 32, 64);
    if (g == 0) {
      xprow[R + r16]      = p0 + b4f;
      xprow[R + 16 + r16] = p1 + b4f;
    }
  }
}

// ---------------------------------------------------------------------------
// final_reduce: out[b] = lr_b + sum_f xp[f][b] * lr_w[f]   (64 blocks)
// ---------------------------------------------------------------------------
__global__ void final_reduce(const float* __restrict__ xp,
                             const float* __restrict__ lr_w,
                             const float* __restrict__ lr_b,
                             float* __restrict__ out) {
  __shared__ float lw[F_DIM];
  __shared__ float part[4][64];
  int t = threadIdx.x;   // 256
  if (t < F_DIM) lw[t] = lr_w[t];
  __syncthreads();
  int q = t >> 6, bl = t & 63;
  int b = blockIdx.x * 64 + bl;
  float acc = 0.f;
#pragma unroll 8
  for (int j = 0; j < 64; ++j) {
    int ff = q * 64 + j;
    acc += xp[(size_t)ff * B_DIM + b] * lw[ff];
  }
  part[q][bl] = acc;
  __syncthreads();
  if (q == 0)
    out[b] = part[0][bl] + part[1][bl] + part[2][bl] + part[3][bl] + lr_b[0];
}

// ---------------------------------------------------------------------------
extern "C" void kernel_launch(void* const* d_in, const int* in_sizes, int n_in,
                              void* d_out, int out_size, void* d_ws, size_t ws_size,
                              hipStream_t stream) {
  (void)in_sizes; (void)n_in; (void)out_size; (void)ws_size;
  const float* x    = (const float*)d_in[0];
  const float* w1   = (const float*)d_in[1];
  const float* b1   = (const float*)d_in[2];
  const float* w2   = (const float*)d_in[3];
  const float* b2   = (const float*)d_in[4];
  const float* w3   = (const float*)d_in[5];
  const float* b3   = (const float*)d_in[6];
  const float* w4   = (const float*)d_in[7];
  const float* b4   = (const float*)d_in[8];
  const float* lr_w = (const float*)d_in[9];
  const float* lr_b = (const float*)d_in[10];
  float* out = (float*)d_out;

  // ws layout: wTs 16 MiB | xT 4 MiB | xp 4 MiB
  char* ws = (char*)d_ws;
  unsigned int* wTs = (unsigned int*)ws;
  float* xT = (float*)(ws + (16u << 20));
  float* xp = (float*)(ws + (16u << 20) + (4u << 20));

  prep_w<<<512, 256, 0, stream>>>(w2, w3, wTs);
  prep_x<<<256, 256, 0, stream>>>(x, xT);
  mlp_persist<<<256, 512, 0, stream>>>(xT, w1, b1, b2, b3, w4, b4, wTs, xp);
  final_reduce<<<64, 256, 0, stream>>>(xp, lr_w, lr_b, out);
}

// Round 4
// 105.706 us; speedup vs baseline: 3.8939x; 3.8939x over previous
//
#include <hip/hip_runtime.h>
#include <hip/hip_bf16.h>

#define F_DIM 256
#define N_DIM 128
#define B_DIM 4096

typedef float f32x4v __attribute__((ext_vector_type(4)));
typedef float f32x16v __attribute__((ext_vector_type(16)));
typedef short s16x8 __attribute__((ext_vector_type(8)));
typedef unsigned int u32x4v __attribute__((ext_vector_type(4)));

__device__ __forceinline__ unsigned short f2bf(float f) {
  union { float f; unsigned u; } v; v.f = f;
  unsigned r = v.u + 0x7fffu + ((v.u >> 16) & 1u);   // RNE
  return (unsigned short)(r >> 16);
}

// packed f32 pair -> bf16x2 dword (fuses to v_cvt_pk_bf16_f32)
__device__ __forceinline__ unsigned pk2(float a, float b) {
  union { __hip_bfloat16 h[2]; unsigned u; } v;
  v.h[0] = __float2bfloat16(a);
  v.h[1] = __float2bfloat16(b);
  return v.u;
}

__device__ __forceinline__ void gload16(const void* g, void* l) {
  __builtin_amdgcn_global_load_lds(
      (const __attribute__((address_space(1))) unsigned int*)g,
      (__attribute__((address_space(3))) unsigned int*)l, 16, 0, 0);
}

// A-fragment with only dword0 populated (k=0,1 slots of a rank-1/rank-2 MFMA)
__device__ __forceinline__ s16x8 frag1(unsigned d) {
  u32x4v v = {d, 0u, 0u, 0u};
  return __builtin_bit_cast(s16x8, v);
}

// 32x32 f32 accumulator -> relu -> bf16 -> two B-fragments (K-steps) of the
// next MFMA, entirely in registers. D layout: row=(r&3)+8*(r>>2)+4*hi.
// B layout: k=8*hi+j. Bridged by 8 cvt_pk + 4 permlane32_swap:
//   swap(P0,P2): d0 = rows(0,1)|(8,9), d2 = rows(4,5)|(12,13), etc.
__device__ __forceinline__ void cvt_swap(f32x16v a, s16x8* f0, s16x8* f1) {
  unsigned P[8];
#pragma unroll
  for (int q = 0; q < 8; ++q)
    P[q] = pk2(fmaxf(a[2 * q], 0.f), fmaxf(a[2 * q + 1], 0.f));
  asm volatile("v_permlane32_swap_b32 %0, %1" : "+v"(P[0]), "+v"(P[2]));
  asm volatile("v_permlane32_swap_b32 %0, %1" : "+v"(P[1]), "+v"(P[3]));
  asm volatile("v_permlane32_swap_b32 %0, %1" : "+v"(P[4]), "+v"(P[6]));
  asm volatile("v_permlane32_swap_b32 %0, %1" : "+v"(P[5]), "+v"(P[7]));
  u32x4v lo = {P[0], P[1], P[2], P[3]};
  u32x4v hh = {P[4], P[5], P[6], P[7]};
  *f0 = __builtin_bit_cast(s16x8, lo);
  *f1 = __builtin_bit_cast(s16x8, hh);
}

// ---------------------------------------------------------------------------
// prep_w: w2,w3 (F,128,128) fp32 [i][o] -> per-feature bf16 W^T [o][i],
// row stride 256B, PRE-SWIZZLED with 16B-slot XOR (o&15) so a linear
// global_load_lds reproduces the swizzled LDS image for 32-row A-frag reads.
// ---------------------------------------------------------------------------
__global__ void prep_w(const float* __restrict__ w2, const float* __restrict__ w3,
                       unsigned int* __restrict__ wTs) {
  __shared__ float tile[128 * 130];
  int m = blockIdx.x;
  const float* src = (m < 256) ? (w2 + (size_t)m * 16384)
                               : (w3 + (size_t)(m - 256) * 16384);
  int t = threadIdx.x;  // 256
  for (int k = 0; k < 64; ++k) {
    int idx = k * 256 + t;
    int i = idx >> 7, o = idx & 127;
    tile[o * 130 + i] = src[idx];
  }
  __syncthreads();
  unsigned int* dst = wTs + (size_t)m * 8192;
  for (int k = 0; k < 32; ++k) {
    int idx = k * 256 + t;
    int o = idx >> 6, i2 = idx & 63;
    unsigned pk = (unsigned)f2bf(tile[o * 130 + 2 * i2]) |
                  ((unsigned)f2bf(tile[o * 130 + 2 * i2 + 1]) << 16);
    dst[(o * 64 + i2) ^ ((o & 15) << 2)] = pk;
  }
}

// ---------------------------------------------------------------------------
// prep_x: x (B,F) -> xT (F,B) fp32
// ---------------------------------------------------------------------------
__global__ void prep_x(const float* __restrict__ x, float* __restrict__ xT) {
  __shared__ float tile[64][65];
  int btile = blockIdx.x & 63;
  int ftile = blockIdx.x >> 6;
  int t = threadIdx.x;  // 256
  for (int k = 0; k < 16; ++k) {
    int idx = k * 256 + t;
    int r = idx >> 6, c = idx & 63;
    tile[r][c] = x[(size_t)(btile * 64 + r) * F_DIM + ftile * 64 + c];
  }
  __syncthreads();
  for (int k = 0; k < 16; ++k) {
    int idx = k * 256 + t;
    int fr = idx >> 6, br = idx & 63;
    xT[(size_t)(ftile * 64 + fr) * B_DIM + btile * 64 + br] = tile[br][fr];
  }
}

// ---------------------------------------------------------------------------
// mlp_chain: 512 blocks = (feature f) x (batch half). 512 thr = 8 waves.
// Each wave owns 32 batch cols per iter, 8 iters. The whole layer chain is
// MFMA 32x32x16 with in-register relu/cvt/permlane bridging; only the W2/W3
// A-fragments come from LDS. No barriers in the loop.
//   H1 = relu(mfma((w1,b1)-frag, (x,1)-frag))           rank-2 outer MFMA
//   acc2 = mfma(W2^T, H1frags, C=b2 via rank-1 MFMA)    8 K-steps
//   acc3 = mfma(W3^T, H2frags, C=b3 via rank-1 MFMA)    8 K-steps
//   y = sum relu(acc3)*w4  (VALU) + shfl_xor(32)
// ---------------------------------------------------------------------------
__global__ __launch_bounds__(512, 2) void mlp_chain(
    const float* __restrict__ xT, const float* __restrict__ w1,
    const float* __restrict__ b1, const float* __restrict__ b2,
    const float* __restrict__ b3, const float* __restrict__ w4,
    const float* __restrict__ b4, const unsigned int* __restrict__ wTs,
    float* __restrict__ xp) {
  __shared__ __align__(16) char Wb[2][128 * 256];   // 64 KiB swizzled W2^T,W3^T
  __shared__ __align__(16) float w4l[N_DIM];

  const int f    = blockIdx.x >> 1;
  const int half = blockIdx.x & 1;
  const int t    = threadIdx.x;
  const int lane = t & 63, wid = t >> 6;
  const int c32  = lane & 31, hi = lane >> 5;

  // ---- stage W2[f], W3[f] (pre-swizzled bf16) -> LDS, linear gload ----
  {
    const char* s2 = (const char*)(wTs + (size_t)f * 8192);
    const char* s3 = (const char*)(wTs + (size_t)(256 + f) * 8192);
#pragma unroll
    for (int c = 0; c < 4; ++c) {
      int off = (wid * 4 + c) * 1024;
      gload16(s2 + off + lane * 16, &Wb[0][off]);
    }
#pragma unroll
    for (int c = 0; c < 4; ++c) {
      int off = (wid * 4 + c) * 1024;
      gload16(s3 + off + lane * 16, &Wb[1][off]);
    }
    if (t < 32) *(f32x4v*)&w4l[t * 4] = *(const f32x4v*)&w4[f * N_DIM + t * 4];
  }

  // ---- persistent rank-1/2 A-fragments (4 dwords each) ----
  unsigned a1d[4], a2d[4], a3d[4];
#pragma unroll
  for (int it = 0; it < 4; ++it) {
    int i = it * 32 + c32;
    float w1v = w1[f * N_DIM + i], b1v = b1[f * N_DIM + i];
    float b2v = b2[f * N_DIM + i], b3v = b3[f * N_DIM + i];
    a1d[it] = hi ? 0u : pk2(w1v, b1v);
    a2d[it] = hi ? 0u : pk2(0.f, b2v);
    a3d[it] = hi ? 0u : pk2(0.f, b3v);
  }
  const float b4f = b4[f];
  const float* xcol = xT + (size_t)f * B_DIM + half * 2048;
  float* xprow = xp + (size_t)f * B_DIM + half * 2048;

  // per-lane swizzled W base: row (c32) * 256 + 16B-slot ((l&15)^hi)
  const int wbase = c32 * 256 + (((lane & 15) ^ hi) << 4);

  __syncthreads();   // the only block-wide barrier

  const f32x16v zero = {0.f, 0.f, 0.f, 0.f, 0.f, 0.f, 0.f, 0.f,
                        0.f, 0.f, 0.f, 0.f, 0.f, 0.f, 0.f, 0.f};

  float xv = xcol[wid * 32 + c32];
#pragma unroll 1
  for (int itb = 0; itb < 8; ++itb) {
    const int bb = itb * 256 + wid * 32;
    s16x8 Bx = frag1(hi ? 0u : pk2(xv, 1.0f));
    float xv_n = (itb < 7) ? xcol[bb + 256 + c32] : 0.f;   // prefetch next

    // ---- layer 1: H1 fragments via rank-2 outer MFMA ----
    s16x8 h1f[8];
#pragma unroll
    for (int it = 0; it < 4; ++it) {
      f32x16v h = __builtin_amdgcn_mfma_f32_32x32x16_bf16(frag1(a1d[it]), Bx,
                                                          zero, 0, 0, 0);
      cvt_swap(h, &h1f[2 * it], &h1f[2 * it + 1]);
    }

    // ---- layers 2+3 chained, 32 neurons (one L2 tile) at a time ----
    f32x16v acc3[4];
#pragma unroll
    for (int nt = 0; nt < 4; ++nt) {
      f32x16v a2 = __builtin_amdgcn_mfma_f32_32x32x16_bf16(frag1(a2d[nt]), Bx,
                                                           zero, 0, 0, 0);
#pragma unroll
      for (int m = 0; m < 8; ++m) {
        s16x8 af = *(const s16x8*)(&Wb[0][0] + nt * 8192 + (wbase ^ (m << 5)));
        a2 = __builtin_amdgcn_mfma_f32_32x32x16_bf16(af, h1f[m], a2, 0, 0, 0);
      }
      s16x8 h2a, h2b;
      cvt_swap(a2, &h2a, &h2b);
#pragma unroll
      for (int n3 = 0; n3 < 4; ++n3) {
        if (nt == 0)
          acc3[n3] = __builtin_amdgcn_mfma_f32_32x32x16_bf16(frag1(a3d[n3]), Bx,
                                                             zero, 0, 0, 0);
        s16x8 af0 = *(const s16x8*)(&Wb[1][0] + n3 * 8192 +
                                    (wbase ^ ((2 * nt) << 5)));
        acc3[n3] = __builtin_amdgcn_mfma_f32_32x32x16_bf16(af0, h2a, acc3[n3],
                                                           0, 0, 0);
        s16x8 af1 = *(const s16x8*)(&Wb[1][0] + n3 * 8192 +
                                    (wbase ^ ((2 * nt + 1) << 5)));
        acc3[n3] = __builtin_amdgcn_mfma_f32_32x32x16_bf16(af1, h2b, acc3[n3],
                                                           0, 0, 0);
      }
    }

    // ---- layer 4 (fp32): y = relu(acc3) . w4, halves joined by shfl ----
    float p = 0.f;
#pragma unroll
    for (int n3 = 0; n3 < 4; ++n3)
#pragma unroll
      for (int q = 0; q < 4; ++q) {
        f32x4v wv = *(const f32x4v*)&w4l[n3 * 32 + q * 8 + hi * 4];
#pragma unroll
        for (int i = 0; i < 4; ++i)
          p = fmaf(fmaxf(acc3[n3][4 * q + i], 0.f), wv[i], p);
      }
    p += __shfl_xor(p, 32, 64);
    if (hi == 0) xprow[bb + c32] = p + b4f;
    xv = xv_n;
  }
}

// ---------------------------------------------------------------------------
// final_reduce: out[b] = lr_b + sum_f xp[f][b] * lr_w[f]
// ---------------------------------------------------------------------------
__global__ void final_reduce(const float* __restrict__ xp,
                             const float* __restrict__ lr_w,
                             const float* __restrict__ lr_b,
                             float* __restrict__ out) {
  __shared__ float lw[F_DIM];
  __shared__ float part[4][64];
  int t = threadIdx.x;   // 256
  if (t < F_DIM) lw[t] = lr_w[t];
  __syncthreads();
  int q = t >> 6, bl = t & 63;
  int b = blockIdx.x * 64 + bl;
  float acc = 0.f;
#pragma unroll 8
  for (int j = 0; j < 64; ++j) {
    int ff = q * 64 + j;
    acc += xp[(size_t)ff * B_DIM + b] * lw[ff];
  }
  part[q][bl] = acc;
  __syncthreads();
  if (q == 0)
    out[b] = part[0][bl] + part[1][bl] + part[2][bl] + part[3][bl] + lr_b[0];
}

// ---------------------------------------------------------------------------
extern "C" void kernel_launch(void* const* d_in, const int* in_sizes, int n_in,
                              void* d_out, int out_size, void* d_ws, size_t ws_size,
                              hipStream_t stream) {
  (void)in_sizes; (void)n_in; (void)out_size; (void)ws_size;
  const float* x    = (const float*)d_in[0];
  const float* w1   = (const float*)d_in[1];
  const float* b1   = (const float*)d_in[2];
  const float* w2   = (const float*)d_in[3];
  const float* b2   = (const float*)d_in[4];
  const float* w3   = (const float*)d_in[5];
  const float* b3   = (const float*)d_in[6];
  const float* w4   = (const float*)d_in[7];
  const float* b4   = (const float*)d_in[8];
  const float* lr_w = (const float*)d_in[9];
  const float* lr_b = (const float*)d_in[10];
  float* out = (float*)d_out;

  // ws layout: wTs 16 MiB | xT 4 MiB | xp 4 MiB
  char* ws = (char*)d_ws;
  unsigned int* wTs = (unsigned int*)ws;
  float* xT = (float*)(ws + (16u << 20));
  float* xp = (float*)(ws + (16u << 20) + (4u << 20));

  prep_w<<<512, 256, 0, stream>>>(w2, w3, wTs);
  prep_x<<<256, 256, 0, stream>>>(x, xT);
  mlp_chain<<<512, 512, 0, stream>>>(xT, w1, b1, b2, b3, w4, b4, wTs, xp);
  final_reduce<<<64, 256, 0, stream>>>(xp, lr_w, lr_b, out);
}

// Round 5
// 103.263 us; speedup vs baseline: 3.9860x; 1.0237x over previous
//
#include <hip/hip_runtime.h>
#include <hip/hip_bf16.h>

#define F_DIM 256
#define N_DIM 128
#define B_DIM 4096

typedef float f32x4v __attribute__((ext_vector_type(4)));
typedef float f32x16v __attribute__((ext_vector_type(16)));
typedef short s16x8 __attribute__((ext_vector_type(8)));
typedef unsigned int u32x4v __attribute__((ext_vector_type(4)));

__device__ __forceinline__ unsigned short f2bf(float f) {
  union { float f; unsigned u; } v; v.f = f;
  unsigned r = v.u + 0x7fffu + ((v.u >> 16) & 1u);   // RNE
  return (unsigned short)(r >> 16);
}

// packed f32 pair -> bf16x2 dword (fuses to v_cvt_pk_bf16_f32)
__device__ __forceinline__ unsigned pk2(float a, float b) {
  union { __hip_bfloat16 h[2]; unsigned u; } v;
  v.h[0] = __float2bfloat16(a);
  v.h[1] = __float2bfloat16(b);
  return v.u;
}

__device__ __forceinline__ void gload16(const void* g, void* l) {
  __builtin_amdgcn_global_load_lds(
      (const __attribute__((address_space(1))) unsigned int*)g,
      (__attribute__((address_space(3))) unsigned int*)l, 16, 0, 0);
}

// A-fragment with only dword0 populated (k=0,1 slots of a rank-1/2 MFMA)
__device__ __forceinline__ s16x8 frag1(unsigned d) {
  u32x4v v = {d, 0u, 0u, 0u};
  return __builtin_bit_cast(s16x8, v);
}

// 32x32 f32 accumulator -> relu -> bf16 -> two B-fragments (K-steps) of the
// next MFMA, entirely in registers: 8 cvt_pk + 4 permlane32_swap.
__device__ __forceinline__ void cvt_swap(f32x16v a, s16x8* f0, s16x8* f1) {
  unsigned P[8];
#pragma unroll
  for (int q = 0; q < 8; ++q)
    P[q] = pk2(fmaxf(a[2 * q], 0.f), fmaxf(a[2 * q + 1], 0.f));
  asm("v_permlane32_swap_b32 %0, %1" : "+v"(P[0]), "+v"(P[2]));
  asm("v_permlane32_swap_b32 %0, %1" : "+v"(P[1]), "+v"(P[3]));
  asm("v_permlane32_swap_b32 %0, %1" : "+v"(P[4]), "+v"(P[6]));
  asm("v_permlane32_swap_b32 %0, %1" : "+v"(P[5]), "+v"(P[7]));
  u32x4v lo = {P[0], P[1], P[2], P[3]};
  u32x4v hh = {P[4], P[5], P[6], P[7]};
  *f0 = __builtin_bit_cast(s16x8, lo);
  *f1 = __builtin_bit_cast(s16x8, hh);
}

// ---------------------------------------------------------------------------
// prep_w: w2,w3 (F,128,128) fp32 [i][o] -> per-feature bf16 W^T [o][i],
// row stride 256B, PRE-SWIZZLED with 16B-slot XOR (o&15) so a linear
// global_load_lds reproduces the swizzled LDS image for 32-row A-frag reads.
// ---------------------------------------------------------------------------
__global__ void prep_w(const float* __restrict__ w2, const float* __restrict__ w3,
                       unsigned int* __restrict__ wTs) {
  __shared__ float tile[128 * 130];
  int m = blockIdx.x;
  const float* src = (m < 256) ? (w2 + (size_t)m * 16384)
                               : (w3 + (size_t)(m - 256) * 16384);
  int t = threadIdx.x;  // 256
  for (int k = 0; k < 64; ++k) {
    int idx = k * 256 + t;
    int i = idx >> 7, o = idx & 127;
    tile[o * 130 + i] = src[idx];
  }
  __syncthreads();
  unsigned int* dst = wTs + (size_t)m * 8192;
  for (int k = 0; k < 32; ++k) {
    int idx = k * 256 + t;
    int o = idx >> 6, i2 = idx & 63;
    unsigned pk = (unsigned)f2bf(tile[o * 130 + 2 * i2]) |
                  ((unsigned)f2bf(tile[o * 130 + 2 * i2 + 1]) << 16);
    dst[(o * 64 + i2) ^ ((o & 15) << 2)] = pk;
  }
}

// ---------------------------------------------------------------------------
// prep_x: x (B,F) -> xT (F,B) fp32
// ---------------------------------------------------------------------------
__global__ void prep_x(const float* __restrict__ x, float* __restrict__ xT) {
  __shared__ float tile[64][65];
  int btile = blockIdx.x & 63;
  int ftile = blockIdx.x >> 6;
  int t = threadIdx.x;  // 256
  for (int k = 0; k < 16; ++k) {
    int idx = k * 256 + t;
    int r = idx >> 6, c = idx & 63;
    tile[r][c] = x[(size_t)(btile * 64 + r) * F_DIM + ftile * 64 + c];
  }
  __syncthreads();
  for (int k = 0; k < 16; ++k) {
    int idx = k * 256 + t;
    int fr = idx >> 6, br = idx & 63;
    xT[(size_t)(ftile * 64 + fr) * B_DIM + btile * 64 + br] = tile[br][fr];
  }
}

// ---------------------------------------------------------------------------
// mlp_chain: 1024 blocks = (feature f) x (batch quarter). 256 thr = 4 waves.
// Each wave runs TWO 32-col batch sets (A,B) per iter so every W fragment
// read from LDS feeds two MFMAs (halves LDS traffic vs r4). Phased
// structure (L1 -> h1, L2 -> h2, L3+L4 per output tile) keeps peak register
// liveness ~200 VGPR. No barriers in the loop.
// ---------------------------------------------------------------------------
__global__ __launch_bounds__(256, 2) void mlp_chain(
    const float* __restrict__ xT, const float* __restrict__ w1,
    const float* __restrict__ b1, const float* __restrict__ b2,
    const float* __restrict__ b3, const float* __restrict__ w4,
    const float* __restrict__ b4, const unsigned int* __restrict__ wTs,
    float* __restrict__ xp) {
  __shared__ __align__(16) char Wb[2][128 * 256];   // 64 KiB swizzled W2^T,W3^T
  __shared__ __align__(16) float w4l[N_DIM];

  const int f  = blockIdx.x >> 2;
  const int qt = blockIdx.x & 3;
  const int t  = threadIdx.x;
  const int lane = t & 63, wid = t >> 6;           // 4 waves
  const int c32 = lane & 31, hi = lane >> 5;

  // ---- stage W2[f], W3[f] (pre-swizzled bf16) -> LDS, linear gload ----
  {
    const char* s2 = (const char*)(wTs + (size_t)f * 8192);
    const char* s3 = (const char*)(wTs + (size_t)(256 + f) * 8192);
#pragma unroll
    for (int c = 0; c < 8; ++c) {
      int off = (wid * 8 + c) * 1024;
      gload16(s2 + off + lane * 16, &Wb[0][off]);
    }
#pragma unroll
    for (int c = 0; c < 8; ++c) {
      int off = (wid * 8 + c) * 1024;
      gload16(s3 + off + lane * 16, &Wb[1][off]);
    }
    if (t < 32) *(f32x4v*)&w4l[t * 4] = *(const f32x4v*)&w4[f * N_DIM + t * 4];
  }

  // ---- persistent rank-1/2 A-fragment dwords ----
  unsigned a1d[4], a2d[4], a3d[4];
#pragma unroll
  for (int it = 0; it < 4; ++it) {
    int i = it * 32 + c32;
    float w1v = w1[f * N_DIM + i], b1v = b1[f * N_DIM + i];
    float b2v = b2[f * N_DIM + i], b3v = b3[f * N_DIM + i];
    a1d[it] = hi ? 0u : pk2(w1v, b1v);
    a2d[it] = hi ? 0u : pk2(0.f, b2v);
    a3d[it] = hi ? 0u : pk2(0.f, b3v);
  }
  const float b4f = b4[f];
  const float* xcol = xT + (size_t)f * B_DIM + qt * 1024;
  float* xprow = xp + (size_t)f * B_DIM + qt * 1024;

  // per-lane swizzled W base: row (c32)*256 + 16B-slot ((lane&15)^hi)
  const int wbase = c32 * 256 + (((lane & 15) ^ hi) << 4);

  __syncthreads();   // the only block-wide barrier

  const f32x16v zero = {0.f, 0.f, 0.f, 0.f, 0.f, 0.f, 0.f, 0.f,
                        0.f, 0.f, 0.f, 0.f, 0.f, 0.f, 0.f, 0.f};

  float xvA = xcol[wid * 64 + c32];
  float xvB = xcol[wid * 64 + 32 + c32];
#pragma unroll 1
  for (int itb = 0; itb < 4; ++itb) {
    const int bb = itb * 256 + wid * 64;
    s16x8 BxA = frag1(hi ? 0u : pk2(xvA, 1.0f));
    s16x8 BxB = frag1(hi ? 0u : pk2(xvB, 1.0f));
    float xvA_n = (itb < 3) ? xcol[bb + 256 + c32] : 0.f;
    float xvB_n = (itb < 3) ? xcol[bb + 256 + 32 + c32] : 0.f;

    // ---- layer 1: H1 fragments via rank-2 outer MFMA ----
    s16x8 h1A[8], h1B[8];
#pragma unroll
    for (int it = 0; it < 4; ++it) {
      f32x16v hA = __builtin_amdgcn_mfma_f32_32x32x16_bf16(frag1(a1d[it]), BxA,
                                                           zero, 0, 0, 0);
      cvt_swap(hA, &h1A[2 * it], &h1A[2 * it + 1]);
      f32x16v hB = __builtin_amdgcn_mfma_f32_32x32x16_bf16(frag1(a1d[it]), BxB,
                                                           zero, 0, 0, 0);
      cvt_swap(hB, &h1B[2 * it], &h1B[2 * it + 1]);
    }

    // ---- layer 2: all four 32-neuron tiles -> H2 fragments ----
    s16x8 h2A[8], h2B[8];
#pragma unroll
    for (int nt = 0; nt < 4; ++nt) {
      f32x16v a2A = __builtin_amdgcn_mfma_f32_32x32x16_bf16(frag1(a2d[nt]), BxA,
                                                            zero, 0, 0, 0);
      f32x16v a2B = __builtin_amdgcn_mfma_f32_32x32x16_bf16(frag1(a2d[nt]), BxB,
                                                            zero, 0, 0, 0);
#pragma unroll
      for (int m = 0; m < 8; ++m) {
        s16x8 af = *(const s16x8*)(&Wb[0][0] + nt * 8192 + (wbase ^ (m << 5)));
        a2A = __builtin_amdgcn_mfma_f32_32x32x16_bf16(af, h1A[m], a2A, 0, 0, 0);
        a2B = __builtin_amdgcn_mfma_f32_32x32x16_bf16(af, h1B[m], a2B, 0, 0, 0);
      }
      cvt_swap(a2A, &h2A[2 * nt], &h2A[2 * nt + 1]);
      cvt_swap(a2B, &h2B[2 * nt], &h2B[2 * nt + 1]);
    }

    // ---- layer 3 + layer 4, one 32-neuron output tile at a time ----
    float pA = 0.f, pB = 0.f;
#pragma unroll
    for (int n3 = 0; n3 < 4; ++n3) {
      f32x16v a3A = __builtin_amdgcn_mfma_f32_32x32x16_bf16(frag1(a3d[n3]), BxA,
                                                            zero, 0, 0, 0);
      f32x16v a3B = __builtin_amdgcn_mfma_f32_32x32x16_bf16(frag1(a3d[n3]), BxB,
                                                            zero, 0, 0, 0);
#pragma unroll
      for (int k = 0; k < 8; ++k) {
        s16x8 af = *(const s16x8*)(&Wb[1][0] + n3 * 8192 + (wbase ^ (k << 5)));
        a3A = __builtin_amdgcn_mfma_f32_32x32x16_bf16(af, h2A[k], a3A, 0, 0, 0);
        a3B = __builtin_amdgcn_mfma_f32_32x32x16_bf16(af, h2B[k], a3B, 0, 0, 0);
      }
#pragma unroll
      for (int q = 0; q < 4; ++q) {
        f32x4v wv = *(const f32x4v*)&w4l[n3 * 32 + q * 8 + hi * 4];
#pragma unroll
        for (int i = 0; i < 4; ++i) {
          pA = fmaf(fmaxf(a3A[4 * q + i], 0.f), wv[i], pA);
          pB = fmaf(fmaxf(a3B[4 * q + i], 0.f), wv[i], pB);
        }
      }
    }
    pA += __shfl_xor(pA, 32, 64);
    pB += __shfl_xor(pB, 32, 64);
    if (hi == 0) {
      xprow[bb + c32]      = pA + b4f;
      xprow[bb + 32 + c32] = pB + b4f;
    }
    xvA = xvA_n;
    xvB = xvB_n;
  }
}

// ---------------------------------------------------------------------------
// final_reduce: out[b] = lr_b + sum_f xp[f][b] * lr_w[f]
// ---------------------------------------------------------------------------
__global__ void final_reduce(const float* __restrict__ xp,
                             const float* __restrict__ lr_w,
                             const float* __restrict__ lr_b,
                             float* __restrict__ out) {
  __shared__ float lw[F_DIM];
  __shared__ float part[4][64];
  int t = threadIdx.x;   // 256
  if (t < F_DIM) lw[t] = lr_w[t];
  __syncthreads();
  int q = t >> 6, bl = t & 63;
  int b = blockIdx.x * 64 + bl;
  float acc = 0.f;
#pragma unroll 8
  for (int j = 0; j < 64; ++j) {
    int ff = q * 64 + j;
    acc += xp[(size_t)ff * B_DIM + b] * lw[ff];
  }
  part[q][bl] = acc;
  __syncthreads();
  if (q == 0)
    out[b] = part[0][bl] + part[1][bl] + part[2][bl] + part[3][bl] + lr_b[0];
}

// ---------------------------------------------------------------------------
extern "C" void kernel_launch(void* const* d_in, const int* in_sizes, int n_in,
                              void* d_out, int out_size, void* d_ws, size_t ws_size,
                              hipStream_t stream) {
  (void)in_sizes; (void)n_in; (void)out_size; (void)ws_size;
  const float* x    = (const float*)d_in[0];
  const float* w1   = (const float*)d_in[1];
  const float* b1   = (const float*)d_in[2];
  const float* w2   = (const float*)d_in[3];
  const float* b2   = (const float*)d_in[4];
  const float* w3   = (const float*)d_in[5];
  const float* b3   = (const float*)d_in[6];
  const float* w4   = (const float*)d_in[7];
  const float* b4   = (const float*)d_in[8];
  const float* lr_w = (const float*)d_in[9];
  const float* lr_b = (const float*)d_in[10];
  float* out = (float*)d_out;

  // ws layout: wTs 16 MiB | xT 4 MiB | xp 4 MiB
  char* ws = (char*)d_ws;
  unsigned int* wTs = (unsigned int*)ws;
  float* xT = (float*)(ws + (16u << 20));
  float* xp = (float*)(ws + (16u << 20) + (4u << 20));

  prep_w<<<512, 256, 0, stream>>>(w2, w3, wTs);
  prep_x<<<256, 256, 0, stream>>>(x, xT);
  mlp_chain<<<1024, 256, 0, stream>>>(xT, w1, b1, b2, b3, w4, b4, wTs, xp);
  final_reduce<<<64, 256, 0, stream>>>(xp, lr_w, lr_b, out);
}